// Round 1
// baseline (451.027 us; speedup 1.0000x reference)
//
#include <hip/hip_runtime.h>

#define D_FEAT 128
#define F4 (D_FEAT / 4)          // 32 float4 per node row
#define BLOCK 1024               // 16 waves
#define FAST_NODES 512           // fast path: register-cached
#define PER_THREAD (FAST_NODES * F4 / BLOCK)  // 16 float4 per thread
#define EPS 1e-6f

__global__ __launch_bounds__(BLOCK, 4) void graphnorm_kernel(
    const float* __restrict__ x,
    const int* __restrict__ n_node,
    const float* __restrict__ mean_scale,
    const float* __restrict__ scale,
    const float* __restrict__ bias,
    float* __restrict__ y,
    int n_graph)
{
    const int g    = blockIdx.x;
    const int t    = threadIdx.x;
    const int lane = t & 63;
    const int wave = t >> 6;     // 0..15
    const int grp  = t & 31;     // which float4 of the 128-feat row
    const int nsub = t >> 5;     // 0..31: node sub-index

    __shared__ int    s_int[16];
    __shared__ float4 s_sum[16][32];
    __shared__ float4 s_sq [16][32];
    __shared__ float4 s_a[32];
    __shared__ float4 s_b[32];
    __shared__ int    s_off;

    // ---- block-local prefix: start node offset of graph g ----
    int my = 0;
    for (int i = t; i < g; i += BLOCK) my += n_node[i];
    #pragma unroll
    for (int o = 32; o; o >>= 1) my += __shfl_down(my, o);
    if (lane == 0) s_int[wave] = my;
    __syncthreads();
    if (t == 0) {
        int tot = 0;
        #pragma unroll
        for (int w = 0; w < 16; w++) tot += s_int[w];
        s_off = tot;
    }
    __syncthreads();
    const int   node0 = s_off;
    const int   cnt   = n_node[g];
    const float inv   = 1.0f / (float)cnt;

    const float4* __restrict__ xg = (const float4*)x + (size_t)node0 * F4;
    float4*       __restrict__ yg = (float4*)y       + (size_t)node0 * F4;

    float4 sum = make_float4(0.f, 0.f, 0.f, 0.f);
    float4 sq  = make_float4(0.f, 0.f, 0.f, 0.f);

    float4 v[PER_THREAD];
    const bool fast = (cnt == FAST_NODES);

    if (fast) {
        // ---- pass 1 (register-cached): coalesced float4 loads ----
        #pragma unroll
        for (int i = 0; i < PER_THREAD; i++) {
            const int node = nsub + 32 * i;
            v[i] = xg[(size_t)node * F4 + grp];
            sum.x += v[i].x; sum.y += v[i].y; sum.z += v[i].z; sum.w += v[i].w;
            sq.x  += v[i].x * v[i].x; sq.y += v[i].y * v[i].y;
            sq.z  += v[i].z * v[i].z; sq.w += v[i].w * v[i].w;
        }
    } else {
        // ---- generic path: streaming accumulate ----
        for (int node = nsub; node < cnt; node += 32) {
            float4 val = xg[(size_t)node * F4 + grp];
            sum.x += val.x; sum.y += val.y; sum.z += val.z; sum.w += val.w;
            sq.x  += val.x * val.x; sq.y += val.y * val.y;
            sq.z  += val.z * val.z; sq.w += val.w * val.w;
        }
    }

    // ---- reduce: lanes 32..63 -> 0..31 within wave ----
    sum.x += __shfl_down(sum.x, 32); sum.y += __shfl_down(sum.y, 32);
    sum.z += __shfl_down(sum.z, 32); sum.w += __shfl_down(sum.w, 32);
    sq.x  += __shfl_down(sq.x, 32);  sq.y  += __shfl_down(sq.y, 32);
    sq.z  += __shfl_down(sq.z, 32);  sq.w  += __shfl_down(sq.w, 32);
    if (lane < 32) { s_sum[wave][lane] = sum; s_sq[wave][lane] = sq; }
    __syncthreads();

    // ---- finalize per-feature coefficients a, b ----
    if (t < 32) {
        float4 S = make_float4(0.f, 0.f, 0.f, 0.f);
        float4 Q = make_float4(0.f, 0.f, 0.f, 0.f);
        #pragma unroll
        for (int w = 0; w < 16; w++) {
            float4 a4 = s_sum[w][t];
            float4 b4 = s_sq[w][t];
            S.x += a4.x; S.y += a4.y; S.z += a4.z; S.w += a4.w;
            Q.x += b4.x; Q.y += b4.y; Q.z += b4.z; Q.w += b4.w;
        }
        const float4 ms = ((const float4*)mean_scale)[t];
        const float4 sc = ((const float4*)scale)[t];
        const float4 bs = ((const float4*)bias)[t];

        float4 A, B;
        {
            float mean = S.x * inv, m = mean * ms.x;
            float var  = Q.x * inv - 2.f * m * mean + m * m;
            A.x = rsqrtf(var + EPS) * sc.x; B.x = bs.x - m * A.x;
        }
        {
            float mean = S.y * inv, m = mean * ms.y;
            float var  = Q.y * inv - 2.f * m * mean + m * m;
            A.y = rsqrtf(var + EPS) * sc.y; B.y = bs.y - m * A.y;
        }
        {
            float mean = S.z * inv, m = mean * ms.z;
            float var  = Q.z * inv - 2.f * m * mean + m * m;
            A.z = rsqrtf(var + EPS) * sc.z; B.z = bs.z - m * A.z;
        }
        {
            float mean = S.w * inv, m = mean * ms.w;
            float var  = Q.w * inv - 2.f * m * mean + m * m;
            A.w = rsqrtf(var + EPS) * sc.w; B.w = bs.w - m * A.w;
        }
        s_a[t] = A; s_b[t] = B;
    }
    __syncthreads();

    const float4 a = s_a[grp];
    const float4 b = s_b[grp];

    if (fast) {
        // ---- pass 2: pure-register affine + coalesced stores ----
        #pragma unroll
        for (int i = 0; i < PER_THREAD; i++) {
            const int node = nsub + 32 * i;
            float4 r;
            r.x = v[i].x * a.x + b.x;
            r.y = v[i].y * a.y + b.y;
            r.z = v[i].z * a.z + b.z;
            r.w = v[i].w * a.w + b.w;
            yg[(size_t)node * F4 + grp] = r;
        }
    } else {
        // ---- generic path: re-read (L2-assisted) ----
        for (int node = nsub; node < cnt; node += 32) {
            float4 val = xg[(size_t)node * F4 + grp];
            float4 r;
            r.x = val.x * a.x + b.x;
            r.y = val.y * a.y + b.y;
            r.z = val.z * a.z + b.z;
            r.w = val.w * a.w + b.w;
            yg[(size_t)node * F4 + grp] = r;
        }
    }
}

extern "C" void kernel_launch(void* const* d_in, const int* in_sizes, int n_in,
                              void* d_out, int out_size, void* d_ws, size_t ws_size,
                              hipStream_t stream) {
    const float* x          = (const float*)d_in[0];
    const int*   n_node     = (const int*)d_in[1];
    const float* mean_scale = (const float*)d_in[2];
    const float* scale      = (const float*)d_in[3];
    const float* bias       = (const float*)d_in[4];
    float*       y          = (float*)d_out;

    const int n_graph = in_sizes[1];

    graphnorm_kernel<<<n_graph, BLOCK, 0, stream>>>(
        x, n_node, mean_scale, scale, bias, y, n_graph);
}